// Round 10
// baseline (144.150 us; speedup 1.0000x reference)
//
#include <hip/hip_runtime.h>
#include <math.h>

#define LSEQ 4096
#define DD 768
#define NST 16
#define RNK 48
#define TCH 16
#define NCH (LSEQ / TCH)   // 256 chunks
#define LTILE 8
#define XPAD 772

__device__ __forceinline__ float softplus_f(float z) {
    return fmaxf(z, 0.0f) + log1pf(expf(-fabsf(z)));
}

__device__ __forceinline__ float soft_clamp_f(float v) {
    const float ctr = 5.00005f;
    const float hr  = 4.99995f;
    const float inv_hr = 1.0f / 4.99995f;
    return ctr + hr * tanhf((v - ctr) * inv_hr);
}

__device__ __forceinline__ float wave_sum(float v) {
    #pragma unroll
    for (int m = 32; m >= 1; m >>= 1) v += __shfl_xor(v, m, 64);
    return v;
}

// ---------------------------------------------------------------------------
// Kernel 1 (v5): projections + delta pipeline.
// Phase A: 6 K-slices x 40 col-pairs (240 thr); LDS 41.6 KB -> 3 blocks/CU.
// ---------------------------------------------------------------------------
__global__ __launch_bounds__(256) void k_proj(
    const float* __restrict__ x, const float* __restrict__ W_bc,
    const float* __restrict__ W_dt, const float* __restrict__ W_dtp,
    const float* __restrict__ b_dt, const float* __restrict__ rms_scale,
    float* __restrict__ delta_out, float* __restrict__ bc_out)
{
    __shared__ __align__(16) float x_s[LTILE][XPAD];     // 24.7 KB
    __shared__ __align__(16) float red[6][LTILE * 80];   // 15.4 KB
    __shared__ __align__(16) float t_lds[LTILE][RNK];    // 1.5 KB
    __shared__ float red2[4][LTILE];

    const int tid = threadIdx.x;
    const int l0  = blockIdx.x * LTILE;

    for (int i = tid; i < LTILE * DD; i += 256) {
        int li = i / DD, d = i - li * DD;
        x_s[li][d] = x[(size_t)(l0 + li) * DD + d];
    }
    __syncthreads();

    if (tid < 240) {
        const int q = tid % 40;          // col pair, j0 = 2q
        const int p = tid / 40;          // K-slice 0..5, d in [128p, 128p+128)
        const int j0 = 2 * q;
        const int dbase = p * 128;
        const int wstride = (j0 < RNK) ? RNK : 32;
        const float* Wb = (j0 < RNK) ? (W_dt + (size_t)dbase * RNK + j0)
                                     : (W_bc + (size_t)dbase * 32 + (j0 - RNK));
        float2 acc[LTILE];
        #pragma unroll
        for (int li = 0; li < LTILE; ++li) acc[li] = make_float2(0.f, 0.f);

        for (int c = 0; c < 32; ++c) {
            const int i4 = c * 4;
            const float* Wp = Wb + (size_t)i4 * wstride;
            float2 wd0 = *(const float2*)(Wp);
            float2 wd1 = *(const float2*)(Wp + wstride);
            float2 wd2 = *(const float2*)(Wp + 2 * wstride);
            float2 wd3 = *(const float2*)(Wp + 3 * wstride);
            #pragma unroll
            for (int li = 0; li < LTILE; ++li) {
                float4 xv = *(const float4*)&x_s[li][dbase + i4];
                acc[li].x = fmaf(xv.x, wd0.x, acc[li].x);
                acc[li].y = fmaf(xv.x, wd0.y, acc[li].y);
                acc[li].x = fmaf(xv.y, wd1.x, acc[li].x);
                acc[li].y = fmaf(xv.y, wd1.y, acc[li].y);
                acc[li].x = fmaf(xv.z, wd2.x, acc[li].x);
                acc[li].y = fmaf(xv.z, wd2.y, acc[li].y);
                acc[li].x = fmaf(xv.w, wd3.x, acc[li].x);
                acc[li].y = fmaf(xv.w, wd3.y, acc[li].y);
            }
        }
        #pragma unroll
        for (int li = 0; li < LTILE; ++li)
            *(float2*)&red[p][li * 80 + j0] = acc[li];
    }
    __syncthreads();

    for (int idx = tid; idx < LTILE * 80; idx += 256) {
        float s = red[0][idx] + red[1][idx] + red[2][idx]
                + red[3][idx] + red[4][idx] + red[5][idx];
        int li = idx / 80, jj = idx - 80 * li;
        if (jj < RNK) t_lds[li][jj] = s;
        else          bc_out[(size_t)(l0 + li) * 32 + (jj - RNK)] = s;
    }
    __syncthreads();

    const int dA = tid, dB = tid + 256, dC = tid + 512;
    float zA[LTILE], zB[LTILE], zC[LTILE];
    {
        float bA = b_dt[dA], bB = b_dt[dB], bC = b_dt[dC];
        #pragma unroll
        for (int li = 0; li < LTILE; ++li) { zA[li] = bA; zB[li] = bB; zC[li] = bC; }
    }
    #pragma unroll 2
    for (int r4 = 0; r4 < RNK; r4 += 4) {
        float wA0 = W_dtp[(r4 + 0) * DD + dA];
        float wA1 = W_dtp[(r4 + 1) * DD + dA];
        float wA2 = W_dtp[(r4 + 2) * DD + dA];
        float wA3 = W_dtp[(r4 + 3) * DD + dA];
        float wB0 = W_dtp[(r4 + 0) * DD + dB];
        float wB1 = W_dtp[(r4 + 1) * DD + dB];
        float wB2 = W_dtp[(r4 + 2) * DD + dB];
        float wB3 = W_dtp[(r4 + 3) * DD + dB];
        float wC0 = W_dtp[(r4 + 0) * DD + dC];
        float wC1 = W_dtp[(r4 + 1) * DD + dC];
        float wC2 = W_dtp[(r4 + 2) * DD + dC];
        float wC3 = W_dtp[(r4 + 3) * DD + dC];
        #pragma unroll
        for (int li = 0; li < LTILE; ++li) {
            float4 t4 = *(const float4*)&t_lds[li][r4];
            zA[li] = fmaf(t4.x, wA0, zA[li]);
            zA[li] = fmaf(t4.y, wA1, zA[li]);
            zA[li] = fmaf(t4.z, wA2, zA[li]);
            zA[li] = fmaf(t4.w, wA3, zA[li]);
            zB[li] = fmaf(t4.x, wB0, zB[li]);
            zB[li] = fmaf(t4.y, wB1, zB[li]);
            zB[li] = fmaf(t4.z, wB2, zB[li]);
            zB[li] = fmaf(t4.w, wB3, zB[li]);
            zC[li] = fmaf(t4.x, wC0, zC[li]);
            zC[li] = fmaf(t4.y, wC1, zC[li]);
            zC[li] = fmaf(t4.z, wC2, zC[li]);
            zC[li] = fmaf(t4.w, wC3, zC[li]);
        }
    }
    #pragma unroll
    for (int li = 0; li < LTILE; ++li) {
        zA[li] = softplus_f(zA[li]);
        zB[li] = softplus_f(zB[li]);
        zC[li] = softplus_f(zC[li]);
    }
    const int wid = tid >> 6;
    const int lane = tid & 63;
    #pragma unroll
    for (int li = 0; li < LTILE; ++li) {
        float ss = wave_sum(zA[li] * zA[li] + zB[li] * zB[li] + zC[li] * zC[li]);
        if (lane == 0) red2[wid][li] = ss;
    }
    __syncthreads();
    {
        float rsA = rms_scale[dA], rsB = rms_scale[dB], rsC = rms_scale[dC];
        #pragma unroll
        for (int li = 0; li < LTILE; ++li) {
            float tot = red2[0][li] + red2[1][li] + red2[2][li] + red2[3][li];
            float inv = rsqrtf(tot * (1.0f / DD) + 1e-6f);
            delta_out[(size_t)(l0 + li) * DD + dA] = soft_clamp_f(zA[li] * inv * rsA);
            delta_out[(size_t)(l0 + li) * DD + dB] = soft_clamp_f(zB[li] * inv * rsB);
            delta_out[(size_t)(l0 + li) * DD + dC] = soft_clamp_f(zC[li] * inv * rsC);
        }
    }
}

// ---------------------------------------------------------------------------
// Scan pass 1 (TCH=16, LDS-staged, full occupancy). Block = 64 d x chunk.
// ---------------------------------------------------------------------------
__global__ __launch_bounds__(256, 8) void k_scan1(
    const float* __restrict__ x, const float* __restrict__ delta,
    const float* __restrict__ bc, const float* __restrict__ A_log,
    float* __restrict__ Pbuf, float* __restrict__ Hbuf)
{
    __shared__ __align__(16) float xs[(TCH + 1) * 64];  // 4.25 KB
    __shared__ __align__(16) float dsv[TCH * 64];       // 4 KB
    __shared__ __align__(16) float bs[TCH * 16];        // 1 KB

    const int tid = threadIdx.x;
    const int db  = blockIdx.x * 64;
    const int c   = blockIdx.y;
    const int l0  = c * TCH;

    for (int i = tid; i < (TCH + 1) * 16; i += 256) {
        int r = i >> 4, f = i & 15;
        int l = l0 - 1 + r;
        float4 v = (l >= 0) ? *(const float4*)&x[(size_t)l * DD + db + f * 4]
                            : make_float4(0.f, 0.f, 0.f, 0.f);
        *(float4*)&xs[r * 64 + f * 4] = v;
    }
    for (int i = tid; i < TCH * 16; i += 256) {
        int r = i >> 4, f = i & 15;
        *(float4*)&dsv[r * 64 + f * 4] =
            *(const float4*)&delta[(size_t)(l0 + r) * DD + db + f * 4];
    }
    if (tid < TCH * 4) {
        int r = tid >> 2, f = tid & 3;
        *(float4*)&bs[r * 16 + f * 4] =
            *(const float4*)&bc[(size_t)(l0 + r) * 32 + f * 4];
    }

    const int lane = tid & 63;
    const int w    = tid >> 6;
    const int q    = lane >> 4;
    const int dlo  = (lane & 15) + w * 16;
    const int d    = db + dlo;

    float An[4];
    {
        float4 a = *(const float4*)&A_log[d * NST + q * 4];
        An[0] = -expf(a.x); An[1] = -expf(a.y);
        An[2] = -expf(a.z); An[3] = -expf(a.w);
    }
    __syncthreads();

    float h[4]  = {0.f, 0.f, 0.f, 0.f};
    float Pp[4] = {1.f, 1.f, 1.f, 1.f};
    float xprev = xs[dlo];

    #pragma unroll 4
    for (int ll = 0; ll < TCH; ++ll) {
        float xv  = xs[(ll + 1) * 64 + dlo];
        float dvc = dsv[ll * 64 + dlo];
        float4 Bc = *(const float4*)&bs[ll * 16 + q * 4];

        float xin = 0.5f * (xv + xprev);
        xprev = xv;
        float c0 = 0.5f * dvc;
        float c1 = sqrtf(dvc) * xin;
        float Bs[4] = {Bc.x, Bc.y, Bc.z, Bc.w};
        #pragma unroll
        for (int n = 0; n < 4; ++n) {
            float denom = fmaf(-c0, An[n], 1.0f);
            float inv = __builtin_amdgcn_rcpf(denom);
            float t1 = 2.0f - denom;
            Pp[n] *= t1 * inv;
            h[n] = fmaf(t1, h[n], c1 * Bs[n]) * inv;
        }
    }
    #pragma unroll
    for (int n = 0; n < 4; ++n) {
        int idx = (c * NST + q * 4 + n) * DD + d;
        Pbuf[idx] = Pp[n];
        Hbuf[idx] = h[n];
    }
}

// ---------------------------------------------------------------------------
// Scan pass 2: one wave per (d,n) series; lane owns 4 chunks.
// Overwrites Pbuf with carry-IN of each chunk.
// ---------------------------------------------------------------------------
__global__ __launch_bounds__(256) void k_scan2(
    float* __restrict__ Pbuf, const float* __restrict__ Hbuf)
{
    const int lane = threadIdx.x & 63;
    const int s = blockIdx.x * 4 + (threadIdx.x >> 6);
    const int d = s % DD;
    const int n = s / DD;

    const int c0 = 4 * lane;
    int idx[4];
    float p[4], hh[4];
    #pragma unroll
    for (int i = 0; i < 4; ++i) {
        idx[i] = ((c0 + i) * NST + n) * DD + d;
        p[i] = Pbuf[idx[i]];
        hh[i] = Hbuf[idx[i]];
    }

    // compose lane's 4 chunks
    float P = p[0], H = hh[0];
    #pragma unroll
    for (int i = 1; i < 4; ++i) {
        H = fmaf(p[i], H, hh[i]);
        P *= p[i];
    }

    #pragma unroll
    for (int ofs = 1; ofs < 64; ofs <<= 1) {
        float Pp = __shfl_up(P, ofs, 64);
        float Hp = __shfl_up(H, ofs, 64);
        if (lane >= ofs) {
            H = fmaf(P, Hp, H);
            P = P * Pp;
        }
    }
    float Hex = __shfl_up(H, 1, 64);
    if (lane == 0) Hex = 0.f;

    float carry = Hex;
    #pragma unroll
    for (int i = 0; i < 4; ++i) {
        Pbuf[idx[i]] = carry;
        carry = fmaf(p[i], carry, hh[i]);
    }
}

// ---------------------------------------------------------------------------
// Scan pass 3 (TCH=16): redo seeded with carry-in; y = sum C*h + D*x.
// ---------------------------------------------------------------------------
__global__ __launch_bounds__(256, 8) void k_scan3(
    const float* __restrict__ x, const float* __restrict__ delta,
    const float* __restrict__ bc, const float* __restrict__ A_log,
    const float* __restrict__ carryin, const float* __restrict__ D_param,
    float* __restrict__ out)
{
    __shared__ __align__(16) float xs[(TCH + 1) * 64];  // 4.25 KB
    __shared__ __align__(16) float dsv[TCH * 64];       // 4 KB
    __shared__ __align__(16) float bs[TCH * 32];        // 2 KB

    const int tid = threadIdx.x;
    const int db  = blockIdx.x * 64;
    const int c   = blockIdx.y;
    const int l0  = c * TCH;

    for (int i = tid; i < (TCH + 1) * 16; i += 256) {
        int r = i >> 4, f = i & 15;
        int l = l0 - 1 + r;
        float4 v = (l >= 0) ? *(const float4*)&x[(size_t)l * DD + db + f * 4]
                            : make_float4(0.f, 0.f, 0.f, 0.f);
        *(float4*)&xs[r * 64 + f * 4] = v;
    }
    for (int i = tid; i < TCH * 16; i += 256) {
        int r = i >> 4, f = i & 15;
        *(float4*)&dsv[r * 64 + f * 4] =
            *(const float4*)&delta[(size_t)(l0 + r) * DD + db + f * 4];
    }
    if (tid < TCH * 8) {
        int r = tid >> 3, f = tid & 7;
        *(float4*)&bs[r * 32 + f * 4] =
            *(const float4*)&bc[(size_t)(l0 + r) * 32 + f * 4];
    }

    const int lane = tid & 63;
    const int w    = tid >> 6;
    const int q    = lane >> 4;
    const int dlo  = (lane & 15) + w * 16;
    const int d    = db + dlo;

    float An[4];
    {
        float4 a = *(const float4*)&A_log[d * NST + q * 4];
        An[0] = -expf(a.x); An[1] = -expf(a.y);
        An[2] = -expf(a.z); An[3] = -expf(a.w);
    }
    float h[4];
    #pragma unroll
    for (int n = 0; n < 4; ++n)
        h[n] = carryin[(c * NST + q * 4 + n) * DD + d];
    const float Dp = D_param[d];

    __syncthreads();

    float xprev = xs[dlo];
    #pragma unroll 4
    for (int ll = 0; ll < TCH; ++ll) {
        float xv  = xs[(ll + 1) * 64 + dlo];
        float dvc = dsv[ll * 64 + dlo];
        float4 Bc = *(const float4*)&bs[ll * 32 + q * 4];
        float4 Cc = *(const float4*)&bs[ll * 32 + 16 + q * 4];

        float xin = 0.5f * (xv + xprev);
        xprev = xv;
        float c0 = 0.5f * dvc;
        float c1 = sqrtf(dvc) * xin;
        float Bs[4] = {Bc.x, Bc.y, Bc.z, Bc.w};
        float Cs[4] = {Cc.x, Cc.y, Cc.z, Cc.w};
        float y = 0.f;
        #pragma unroll
        for (int n = 0; n < 4; ++n) {
            float denom = fmaf(-c0, An[n], 1.0f);
            float inv = __builtin_amdgcn_rcpf(denom);
            float t1 = 2.0f - denom;
            h[n] = fmaf(t1, h[n], c1 * Bs[n]) * inv;
            y = fmaf(Cs[n], h[n], y);
        }
        y += __shfl_xor(y, 16, 64);
        y += __shfl_xor(y, 32, 64);
        if (q == 0)
            out[(size_t)(l0 + ll) * DD + d] = fmaf(Dp, xv, y);
    }
}

extern "C" void kernel_launch(void* const* d_in, const int* in_sizes, int n_in,
                              void* d_out, int out_size, void* d_ws, size_t ws_size,
                              hipStream_t stream) {
    const float* x         = (const float*)d_in[0];
    const float* A_log     = (const float*)d_in[1];
    const float* D_param   = (const float*)d_in[2];
    const float* W_bc      = (const float*)d_in[3];
    const float* W_dt      = (const float*)d_in[4];
    const float* W_dtp     = (const float*)d_in[5];
    const float* b_dt      = (const float*)d_in[6];
    const float* rms_scale = (const float*)d_in[7];
    float* out = (float*)d_out;

    float* ws    = (float*)d_ws;
    float* delta = ws;                               // L*D
    float* bcbuf = delta + (size_t)LSEQ * DD;        // L*32
    float* Pbuf  = bcbuf + (size_t)LSEQ * 32;        // NCH*16*D = 12.6 MB
    float* Hbuf  = Pbuf + (size_t)NCH * NST * DD;    // NCH*16*D

    k_proj<<<LSEQ / LTILE, 256, 0, stream>>>(x, W_bc, W_dt, W_dtp, b_dt,
                                             rms_scale, delta, bcbuf);
    k_scan1<<<dim3(DD / 64, NCH), 256, 0, stream>>>(x, delta, bcbuf, A_log,
                                                    Pbuf, Hbuf);
    k_scan2<<<(DD * NST) / 4, 256, 0, stream>>>(Pbuf, Hbuf);
    k_scan3<<<dim3(DD / 64, NCH), 256, 0, stream>>>(x, delta, bcbuf, A_log,
                                                    Pbuf, D_param, out);
}

// Round 12
// 100.867 us; speedup vs baseline: 1.4291x; 1.4291x over previous
//
#include <hip/hip_runtime.h>
#include <math.h>

#define LSEQ 4096
#define DD 768
#define NST 16
#define RNK 48
#define TCH 16
#define NCH (LSEQ / TCH)   // 256 chunks
#define LTILE 8
#define XPAD 772

__device__ __forceinline__ float softplus_f(float z) {
    return fmaxf(z, 0.0f) + log1pf(expf(-fabsf(z)));
}

__device__ __forceinline__ float soft_clamp_f(float v) {
    const float ctr = 5.00005f;
    const float hr  = 4.99995f;
    const float inv_hr = 1.0f / 4.99995f;
    return ctr + hr * tanhf((v - ctr) * inv_hr);
}

__device__ __forceinline__ float wave_sum(float v) {
    #pragma unroll
    for (int m = 32; m >= 1; m >>= 1) v += __shfl_xor(v, m, 64);
    return v;
}

// ---------------------------------------------------------------------------
// Kernel 1 (v5, unchanged): projections + delta pipeline.
// ---------------------------------------------------------------------------
__global__ __launch_bounds__(256) void k_proj(
    const float* __restrict__ x, const float* __restrict__ W_bc,
    const float* __restrict__ W_dt, const float* __restrict__ W_dtp,
    const float* __restrict__ b_dt, const float* __restrict__ rms_scale,
    float* __restrict__ delta_out, float* __restrict__ bc_out)
{
    __shared__ __align__(16) float x_s[LTILE][XPAD];     // 24.7 KB
    __shared__ __align__(16) float red[6][LTILE * 80];   // 15.4 KB
    __shared__ __align__(16) float t_lds[LTILE][RNK];    // 1.5 KB
    __shared__ float red2[4][LTILE];

    const int tid = threadIdx.x;
    const int l0  = blockIdx.x * LTILE;

    for (int i = tid; i < LTILE * DD; i += 256) {
        int li = i / DD, d = i - li * DD;
        x_s[li][d] = x[(size_t)(l0 + li) * DD + d];
    }
    __syncthreads();

    if (tid < 240) {
        const int q = tid % 40;          // col pair, j0 = 2q
        const int p = tid / 40;          // K-slice 0..5, d in [128p, 128p+128)
        const int j0 = 2 * q;
        const int dbase = p * 128;
        const int wstride = (j0 < RNK) ? RNK : 32;
        const float* Wb = (j0 < RNK) ? (W_dt + (size_t)dbase * RNK + j0)
                                     : (W_bc + (size_t)dbase * 32 + (j0 - RNK));
        float2 acc[LTILE];
        #pragma unroll
        for (int li = 0; li < LTILE; ++li) acc[li] = make_float2(0.f, 0.f);

        for (int c = 0; c < 32; ++c) {
            const int i4 = c * 4;
            const float* Wp = Wb + (size_t)i4 * wstride;
            float2 wd0 = *(const float2*)(Wp);
            float2 wd1 = *(const float2*)(Wp + wstride);
            float2 wd2 = *(const float2*)(Wp + 2 * wstride);
            float2 wd3 = *(const float2*)(Wp + 3 * wstride);
            #pragma unroll
            for (int li = 0; li < LTILE; ++li) {
                float4 xv = *(const float4*)&x_s[li][dbase + i4];
                acc[li].x = fmaf(xv.x, wd0.x, acc[li].x);
                acc[li].y = fmaf(xv.x, wd0.y, acc[li].y);
                acc[li].x = fmaf(xv.y, wd1.x, acc[li].x);
                acc[li].y = fmaf(xv.y, wd1.y, acc[li].y);
                acc[li].x = fmaf(xv.z, wd2.x, acc[li].x);
                acc[li].y = fmaf(xv.z, wd2.y, acc[li].y);
                acc[li].x = fmaf(xv.w, wd3.x, acc[li].x);
                acc[li].y = fmaf(xv.w, wd3.y, acc[li].y);
            }
        }
        #pragma unroll
        for (int li = 0; li < LTILE; ++li)
            *(float2*)&red[p][li * 80 + j0] = acc[li];
    }
    __syncthreads();

    for (int idx = tid; idx < LTILE * 80; idx += 256) {
        float s = red[0][idx] + red[1][idx] + red[2][idx]
                + red[3][idx] + red[4][idx] + red[5][idx];
        int li = idx / 80, jj = idx - 80 * li;
        if (jj < RNK) t_lds[li][jj] = s;
        else          bc_out[(size_t)(l0 + li) * 32 + (jj - RNK)] = s;
    }
    __syncthreads();

    const int dA = tid, dB = tid + 256, dC = tid + 512;
    float zA[LTILE], zB[LTILE], zC[LTILE];
    {
        float bA = b_dt[dA], bB = b_dt[dB], bC = b_dt[dC];
        #pragma unroll
        for (int li = 0; li < LTILE; ++li) { zA[li] = bA; zB[li] = bB; zC[li] = bC; }
    }
    #pragma unroll 2
    for (int r4 = 0; r4 < RNK; r4 += 4) {
        float wA0 = W_dtp[(r4 + 0) * DD + dA];
        float wA1 = W_dtp[(r4 + 1) * DD + dA];
        float wA2 = W_dtp[(r4 + 2) * DD + dA];
        float wA3 = W_dtp[(r4 + 3) * DD + dA];
        float wB0 = W_dtp[(r4 + 0) * DD + dB];
        float wB1 = W_dtp[(r4 + 1) * DD + dB];
        float wB2 = W_dtp[(r4 + 2) * DD + dB];
        float wB3 = W_dtp[(r4 + 3) * DD + dB];
        float wC0 = W_dtp[(r4 + 0) * DD + dC];
        float wC1 = W_dtp[(r4 + 1) * DD + dC];
        float wC2 = W_dtp[(r4 + 2) * DD + dC];
        float wC3 = W_dtp[(r4 + 3) * DD + dC];
        #pragma unroll
        for (int li = 0; li < LTILE; ++li) {
            float4 t4 = *(const float4*)&t_lds[li][r4];
            zA[li] = fmaf(t4.x, wA0, zA[li]);
            zA[li] = fmaf(t4.y, wA1, zA[li]);
            zA[li] = fmaf(t4.z, wA2, zA[li]);
            zA[li] = fmaf(t4.w, wA3, zA[li]);
            zB[li] = fmaf(t4.x, wB0, zB[li]);
            zB[li] = fmaf(t4.y, wB1, zB[li]);
            zB[li] = fmaf(t4.z, wB2, zB[li]);
            zB[li] = fmaf(t4.w, wB3, zB[li]);
            zC[li] = fmaf(t4.x, wC0, zC[li]);
            zC[li] = fmaf(t4.y, wC1, zC[li]);
            zC[li] = fmaf(t4.z, wC2, zC[li]);
            zC[li] = fmaf(t4.w, wC3, zC[li]);
        }
    }
    #pragma unroll
    for (int li = 0; li < LTILE; ++li) {
        zA[li] = softplus_f(zA[li]);
        zB[li] = softplus_f(zB[li]);
        zC[li] = softplus_f(zC[li]);
    }
    const int wid = tid >> 6;
    const int lane = tid & 63;
    #pragma unroll
    for (int li = 0; li < LTILE; ++li) {
        float ss = wave_sum(zA[li] * zA[li] + zB[li] * zB[li] + zC[li] * zC[li]);
        if (lane == 0) red2[wid][li] = ss;
    }
    __syncthreads();
    {
        float rsA = rms_scale[dA], rsB = rms_scale[dB], rsC = rms_scale[dC];
        #pragma unroll
        for (int li = 0; li < LTILE; ++li) {
            float tot = red2[0][li] + red2[1][li] + red2[2][li] + red2[3][li];
            float inv = rsqrtf(tot * (1.0f / DD) + 1e-6f);
            delta_out[(size_t)(l0 + li) * DD + dA] = soft_clamp_f(zA[li] * inv * rsA);
            delta_out[(size_t)(l0 + li) * DD + dB] = soft_clamp_f(zB[li] * inv * rsB);
            delta_out[(size_t)(l0 + li) * DD + dC] = soft_clamp_f(zC[li] * inv * rsC);
        }
    }
}

// ---------------------------------------------------------------------------
// Scan pass 1 (TCH=16, LDS-staged, full occupancy). Block = 64 d x chunk.
// ---------------------------------------------------------------------------
__global__ __launch_bounds__(256, 8) void k_scan1(
    const float* __restrict__ x, const float* __restrict__ delta,
    const float* __restrict__ bc, const float* __restrict__ A_log,
    float* __restrict__ Pbuf, float* __restrict__ Hbuf)
{
    __shared__ __align__(16) float xs[(TCH + 1) * 64];  // 4.25 KB
    __shared__ __align__(16) float dsv[TCH * 64];       // 4 KB
    __shared__ __align__(16) float bs[TCH * 16];        // 1 KB

    const int tid = threadIdx.x;
    const int db  = blockIdx.x * 64;
    const int c   = blockIdx.y;
    const int l0  = c * TCH;

    for (int i = tid; i < (TCH + 1) * 16; i += 256) {
        int r = i >> 4, f = i & 15;
        int l = l0 - 1 + r;
        float4 v = (l >= 0) ? *(const float4*)&x[(size_t)l * DD + db + f * 4]
                            : make_float4(0.f, 0.f, 0.f, 0.f);
        *(float4*)&xs[r * 64 + f * 4] = v;
    }
    for (int i = tid; i < TCH * 16; i += 256) {
        int r = i >> 4, f = i & 15;
        *(float4*)&dsv[r * 64 + f * 4] =
            *(const float4*)&delta[(size_t)(l0 + r) * DD + db + f * 4];
    }
    if (tid < TCH * 4) {
        int r = tid >> 2, f = tid & 3;
        *(float4*)&bs[r * 16 + f * 4] =
            *(const float4*)&bc[(size_t)(l0 + r) * 32 + f * 4];
    }

    const int lane = tid & 63;
    const int w    = tid >> 6;
    const int q    = lane >> 4;
    const int dlo  = (lane & 15) + w * 16;
    const int d    = db + dlo;

    float An[4];
    {
        float4 a = *(const float4*)&A_log[d * NST + q * 4];
        An[0] = -expf(a.x); An[1] = -expf(a.y);
        An[2] = -expf(a.z); An[3] = -expf(a.w);
    }
    __syncthreads();

    float h[4]  = {0.f, 0.f, 0.f, 0.f};
    float Pp[4] = {1.f, 1.f, 1.f, 1.f};
    float xprev = xs[dlo];

    #pragma unroll 4
    for (int ll = 0; ll < TCH; ++ll) {
        float xv  = xs[(ll + 1) * 64 + dlo];
        float dvc = dsv[ll * 64 + dlo];
        float4 Bc = *(const float4*)&bs[ll * 16 + q * 4];

        float xin = 0.5f * (xv + xprev);
        xprev = xv;
        float c0 = 0.5f * dvc;
        float c1 = sqrtf(dvc) * xin;
        float Bs[4] = {Bc.x, Bc.y, Bc.z, Bc.w};
        #pragma unroll
        for (int n = 0; n < 4; ++n) {
            float denom = fmaf(-c0, An[n], 1.0f);
            float inv = __builtin_amdgcn_rcpf(denom);
            float t1 = 2.0f - denom;
            Pp[n] *= t1 * inv;
            h[n] = fmaf(t1, h[n], c1 * Bs[n]) * inv;
        }
    }
    #pragma unroll
    for (int n = 0; n < 4; ++n) {
        int idx = (c * NST + q * 4 + n) * DD + d;
        Pbuf[idx] = Pp[n];
        Hbuf[idx] = h[n];
    }
}

// ---------------------------------------------------------------------------
// Scan pass 2 (v3): serial thread-per-series, coalesced (consecutive threads
// = consecutive d), explicit 8-deep prefetch pipeline to hide L2/HBM latency.
// Overwrites Pbuf with carry-IN of each chunk.
// ---------------------------------------------------------------------------
__global__ __launch_bounds__(64) void k_scan2(
    float* __restrict__ Pbuf, const float* __restrict__ Hbuf)
{
    const int s = blockIdx.x * 64 + threadIdx.x;   // series 0..12287 (d-major)
    const int d = s % DD;
    const int n = s / DD;
    const int stride = NST * DD;

    int idx = n * DD + d;
    int idx_pf = idx;
    float p[8], h[8];
    #pragma unroll
    for (int i = 0; i < 8; ++i) {
        p[i] = Pbuf[idx_pf];
        h[i] = Hbuf[idx_pf];
        idx_pf += stride;
    }

    float carry = 0.f;
    for (int g = 0; g < NCH / 8; ++g) {
        float pn[8], hn[8];
        if (g + 1 < NCH / 8) {
            #pragma unroll
            for (int i = 0; i < 8; ++i) {
                pn[i] = Pbuf[idx_pf];
                hn[i] = Hbuf[idx_pf];
                idx_pf += stride;
            }
        }
        #pragma unroll
        for (int i = 0; i < 8; ++i) {
            Pbuf[idx] = carry;
            carry = fmaf(p[i], carry, h[i]);
            idx += stride;
        }
        #pragma unroll
        for (int i = 0; i < 8; ++i) { p[i] = pn[i]; h[i] = hn[i]; }
    }
}

// ---------------------------------------------------------------------------
// Scan pass 3 (TCH=16): redo seeded with carry-in; y = sum C*h + D*x.
// ---------------------------------------------------------------------------
__global__ __launch_bounds__(256, 8) void k_scan3(
    const float* __restrict__ x, const float* __restrict__ delta,
    const float* __restrict__ bc, const float* __restrict__ A_log,
    const float* __restrict__ carryin, const float* __restrict__ D_param,
    float* __restrict__ out)
{
    __shared__ __align__(16) float xs[(TCH + 1) * 64];  // 4.25 KB
    __shared__ __align__(16) float dsv[TCH * 64];       // 4 KB
    __shared__ __align__(16) float bs[TCH * 32];        // 2 KB

    const int tid = threadIdx.x;
    const int db  = blockIdx.x * 64;
    const int c   = blockIdx.y;
    const int l0  = c * TCH;

    for (int i = tid; i < (TCH + 1) * 16; i += 256) {
        int r = i >> 4, f = i & 15;
        int l = l0 - 1 + r;
        float4 v = (l >= 0) ? *(const float4*)&x[(size_t)l * DD + db + f * 4]
                            : make_float4(0.f, 0.f, 0.f, 0.f);
        *(float4*)&xs[r * 64 + f * 4] = v;
    }
    for (int i = tid; i < TCH * 16; i += 256) {
        int r = i >> 4, f = i & 15;
        *(float4*)&dsv[r * 64 + f * 4] =
            *(const float4*)&delta[(size_t)(l0 + r) * DD + db + f * 4];
    }
    if (tid < TCH * 8) {
        int r = tid >> 3, f = tid & 7;
        *(float4*)&bs[r * 32 + f * 4] =
            *(const float4*)&bc[(size_t)(l0 + r) * 32 + f * 4];
    }

    const int lane = tid & 63;
    const int w    = tid >> 6;
    const int q    = lane >> 4;
    const int dlo  = (lane & 15) + w * 16;
    const int d    = db + dlo;

    float An[4];
    {
        float4 a = *(const float4*)&A_log[d * NST + q * 4];
        An[0] = -expf(a.x); An[1] = -expf(a.y);
        An[2] = -expf(a.z); An[3] = -expf(a.w);
    }
    float h[4];
    #pragma unroll
    for (int n = 0; n < 4; ++n)
        h[n] = carryin[(c * NST + q * 4 + n) * DD + d];
    const float Dp = D_param[d];

    __syncthreads();

    float xprev = xs[dlo];
    #pragma unroll 4
    for (int ll = 0; ll < TCH; ++ll) {
        float xv  = xs[(ll + 1) * 64 + dlo];
        float dvc = dsv[ll * 64 + dlo];
        float4 Bc = *(const float4*)&bs[ll * 32 + q * 4];
        float4 Cc = *(const float4*)&bs[ll * 32 + 16 + q * 4];

        float xin = 0.5f * (xv + xprev);
        xprev = xv;
        float c0 = 0.5f * dvc;
        float c1 = sqrtf(dvc) * xin;
        float Bs[4] = {Bc.x, Bc.y, Bc.z, Bc.w};
        float Cs[4] = {Cc.x, Cc.y, Cc.z, Cc.w};
        float y = 0.f;
        #pragma unroll
        for (int n = 0; n < 4; ++n) {
            float denom = fmaf(-c0, An[n], 1.0f);
            float inv = __builtin_amdgcn_rcpf(denom);
            float t1 = 2.0f - denom;
            h[n] = fmaf(t1, h[n], c1 * Bs[n]) * inv;
            y = fmaf(Cs[n], h[n], y);
        }
        y += __shfl_xor(y, 16, 64);
        y += __shfl_xor(y, 32, 64);
        if (q == 0)
            out[(size_t)(l0 + ll) * DD + d] = fmaf(Dp, xv, y);
    }
}

extern "C" void kernel_launch(void* const* d_in, const int* in_sizes, int n_in,
                              void* d_out, int out_size, void* d_ws, size_t ws_size,
                              hipStream_t stream) {
    const float* x         = (const float*)d_in[0];
    const float* A_log     = (const float*)d_in[1];
    const float* D_param   = (const float*)d_in[2];
    const float* W_bc      = (const float*)d_in[3];
    const float* W_dt      = (const float*)d_in[4];
    const float* W_dtp     = (const float*)d_in[5];
    const float* b_dt      = (const float*)d_in[6];
    const float* rms_scale = (const float*)d_in[7];
    float* out = (float*)d_out;

    float* ws    = (float*)d_ws;
    float* delta = ws;                               // L*D
    float* bcbuf = delta + (size_t)LSEQ * DD;        // L*32
    float* Pbuf  = bcbuf + (size_t)LSEQ * 32;        // NCH*16*D = 12.6 MB
    float* Hbuf  = Pbuf + (size_t)NCH * NST * DD;    // NCH*16*D

    k_proj<<<LSEQ / LTILE, 256, 0, stream>>>(x, W_bc, W_dt, W_dtp, b_dt,
                                             rms_scale, delta, bcbuf);
    k_scan1<<<dim3(DD / 64, NCH), 256, 0, stream>>>(x, delta, bcbuf, A_log,
                                                    Pbuf, Hbuf);
    k_scan2<<<(DD * NST) / 64, 64, 0, stream>>>(Pbuf, Hbuf);
    k_scan3<<<dim3(DD / 64, NCH), 256, 0, stream>>>(x, delta, bcbuf, A_log,
                                                    Pbuf, D_param, out);
}

// Round 13
// 99.664 us; speedup vs baseline: 1.4464x; 1.0121x over previous
//
#include <hip/hip_runtime.h>
#include <math.h>

#define LSEQ 4096
#define DD 768
#define NST 16
#define RNK 48
#define TCH 16
#define NCH (LSEQ / TCH)   // 256 chunks
#define LTILE 8
#define XPAD 772

__device__ __forceinline__ float softplus_f(float z) {
    return fmaxf(z, 0.0f) + log1pf(expf(-fabsf(z)));
}

__device__ __forceinline__ float soft_clamp_f(float v) {
    const float ctr = 5.00005f;
    const float hr  = 4.99995f;
    const float inv_hr = 1.0f / 4.99995f;
    return ctr + hr * tanhf((v - ctr) * inv_hr);
}

__device__ __forceinline__ float wave_sum(float v) {
    #pragma unroll
    for (int m = 32; m >= 1; m >>= 1) v += __shfl_xor(v, m, 64);
    return v;
}

// ---------------------------------------------------------------------------
// Kernel 1 (v6): 512 threads, 12-way split-K (16 c-iters/thread), whole grid
// co-resident (2 blocks/CU, 16 waves/CU). float4 staging.
// ---------------------------------------------------------------------------
__global__ __launch_bounds__(512) void k_proj(
    const float* __restrict__ x, const float* __restrict__ W_bc,
    const float* __restrict__ W_dt, const float* __restrict__ W_dtp,
    const float* __restrict__ b_dt, const float* __restrict__ rms_scale,
    float* __restrict__ delta_out, float* __restrict__ bc_out)
{
    __shared__ __align__(16) float x_s[LTILE][XPAD];     // 24.7 KB
    __shared__ __align__(16) float red[12][LTILE * 80];  // 30 KB
    __shared__ __align__(16) float t_lds[LTILE][RNK];    // 1.5 KB
    __shared__ float red2[8][LTILE];

    const int tid = threadIdx.x;
    const int l0  = blockIdx.x * LTILE;

    // stage x: 1536 float4 = 3 x 512 (x rows contiguous in global)
    {
        const float4* xg = (const float4*)(x + (size_t)l0 * DD);
        #pragma unroll
        for (int k = 0; k < 3; ++k) {
            int idx = k * 512 + tid;
            int li = idx / 192;
            int j  = idx - li * 192;
            *(float4*)&x_s[li][j * 4] = xg[idx];
        }
    }
    __syncthreads();

    // ---- phase A: t (48 cols) + bc (32 cols), 12-way split-K ----
    if (tid < 480) {
        const int q = tid % 40;          // col pair, j0 = 2q
        const int p = tid / 40;          // K-slice 0..11, d in [64p, 64p+64)
        const int j0 = 2 * q;
        const int dbase = p * 64;
        const int wstride = (j0 < RNK) ? RNK : 32;
        const float* Wb = (j0 < RNK) ? (W_dt + (size_t)dbase * RNK + j0)
                                     : (W_bc + (size_t)dbase * 32 + (j0 - RNK));
        float2 acc[LTILE];
        #pragma unroll
        for (int li = 0; li < LTILE; ++li) acc[li] = make_float2(0.f, 0.f);

        #pragma unroll 2
        for (int c = 0; c < 16; ++c) {
            const int i4 = c * 4;
            const float* Wp = Wb + (size_t)i4 * wstride;
            float2 wd0 = *(const float2*)(Wp);
            float2 wd1 = *(const float2*)(Wp + wstride);
            float2 wd2 = *(const float2*)(Wp + 2 * wstride);
            float2 wd3 = *(const float2*)(Wp + 3 * wstride);
            #pragma unroll
            for (int li = 0; li < LTILE; ++li) {
                float4 xv = *(const float4*)&x_s[li][dbase + i4];
                acc[li].x = fmaf(xv.x, wd0.x, acc[li].x);
                acc[li].y = fmaf(xv.x, wd0.y, acc[li].y);
                acc[li].x = fmaf(xv.y, wd1.x, acc[li].x);
                acc[li].y = fmaf(xv.y, wd1.y, acc[li].y);
                acc[li].x = fmaf(xv.z, wd2.x, acc[li].x);
                acc[li].y = fmaf(xv.z, wd2.y, acc[li].y);
                acc[li].x = fmaf(xv.w, wd3.x, acc[li].x);
                acc[li].y = fmaf(xv.w, wd3.y, acc[li].y);
            }
        }
        #pragma unroll
        for (int li = 0; li < LTILE; ++li)
            *(float2*)&red[p][li * 80 + j0] = acc[li];
    }
    __syncthreads();

    // reduce 12 partials -> t_lds / bc_out (640 outputs, 512 threads)
    for (int idx = tid; idx < LTILE * 80; idx += 512) {
        float s = 0.f;
        #pragma unroll
        for (int p = 0; p < 12; ++p) s += red[p][idx];
        int li = idx / 80, jj = idx - 80 * li;
        if (jj < RNK) t_lds[li][jj] = s;
        else          bc_out[(size_t)(l0 + li) * 32 + (jj - RNK)] = s;
    }
    __syncthreads();

    // ---- phase B: delta pipeline, 512 + 256 d's ----
    const int d0 = tid;
    const int d1 = tid + 512;
    const bool has2 = (tid < 256);

    float z0[LTILE], z1[LTILE];
    {
        float bb0 = b_dt[d0];
        float bb1 = has2 ? b_dt[d1] : 0.f;
        #pragma unroll
        for (int li = 0; li < LTILE; ++li) { z0[li] = bb0; z1[li] = bb1; }
    }
    #pragma unroll 2
    for (int r4 = 0; r4 < RNK; r4 += 4) {
        float w00 = W_dtp[(r4 + 0) * DD + d0];
        float w01 = W_dtp[(r4 + 1) * DD + d0];
        float w02 = W_dtp[(r4 + 2) * DD + d0];
        float w03 = W_dtp[(r4 + 3) * DD + d0];
        float w10 = has2 ? W_dtp[(r4 + 0) * DD + d1] : 0.f;
        float w11 = has2 ? W_dtp[(r4 + 1) * DD + d1] : 0.f;
        float w12 = has2 ? W_dtp[(r4 + 2) * DD + d1] : 0.f;
        float w13 = has2 ? W_dtp[(r4 + 3) * DD + d1] : 0.f;
        #pragma unroll
        for (int li = 0; li < LTILE; ++li) {
            float4 t4 = *(const float4*)&t_lds[li][r4];
            z0[li] = fmaf(t4.x, w00, z0[li]);
            z0[li] = fmaf(t4.y, w01, z0[li]);
            z0[li] = fmaf(t4.z, w02, z0[li]);
            z0[li] = fmaf(t4.w, w03, z0[li]);
            z1[li] = fmaf(t4.x, w10, z1[li]);
            z1[li] = fmaf(t4.y, w11, z1[li]);
            z1[li] = fmaf(t4.z, w12, z1[li]);
            z1[li] = fmaf(t4.w, w13, z1[li]);
        }
    }
    #pragma unroll
    for (int li = 0; li < LTILE; ++li) {
        z0[li] = softplus_f(z0[li]);
        z1[li] = has2 ? softplus_f(z1[li]) : 0.f;
    }
    const int wid = tid >> 6;
    const int lane = tid & 63;
    #pragma unroll
    for (int li = 0; li < LTILE; ++li) {
        float ss = wave_sum(z0[li] * z0[li] + z1[li] * z1[li]);
        if (lane == 0) red2[wid][li] = ss;
    }
    __syncthreads();
    {
        float rs0 = rms_scale[d0];
        float rs1 = has2 ? rms_scale[d1] : 0.f;
        #pragma unroll
        for (int li = 0; li < LTILE; ++li) {
            float tot = 0.f;
            #pragma unroll
            for (int k = 0; k < 8; ++k) tot += red2[k][li];
            float inv = rsqrtf(tot * (1.0f / DD) + 1e-6f);
            delta_out[(size_t)(l0 + li) * DD + d0] = soft_clamp_f(z0[li] * inv * rs0);
            if (has2)
                delta_out[(size_t)(l0 + li) * DD + d1] = soft_clamp_f(z1[li] * inv * rs1);
        }
    }
}

// ---------------------------------------------------------------------------
// Scan pass 1 (TCH=16, LDS-staged, full occupancy). Block = 64 d x chunk.
// ---------------------------------------------------------------------------
__global__ __launch_bounds__(256, 8) void k_scan1(
    const float* __restrict__ x, const float* __restrict__ delta,
    const float* __restrict__ bc, const float* __restrict__ A_log,
    float* __restrict__ Pbuf, float* __restrict__ Hbuf)
{
    __shared__ __align__(16) float xs[(TCH + 1) * 64];  // 4.25 KB
    __shared__ __align__(16) float dsv[TCH * 64];       // 4 KB
    __shared__ __align__(16) float bs[TCH * 16];        // 1 KB

    const int tid = threadIdx.x;
    const int db  = blockIdx.x * 64;
    const int c   = blockIdx.y;
    const int l0  = c * TCH;

    for (int i = tid; i < (TCH + 1) * 16; i += 256) {
        int r = i >> 4, f = i & 15;
        int l = l0 - 1 + r;
        float4 v = (l >= 0) ? *(const float4*)&x[(size_t)l * DD + db + f * 4]
                            : make_float4(0.f, 0.f, 0.f, 0.f);
        *(float4*)&xs[r * 64 + f * 4] = v;
    }
    for (int i = tid; i < TCH * 16; i += 256) {
        int r = i >> 4, f = i & 15;
        *(float4*)&dsv[r * 64 + f * 4] =
            *(const float4*)&delta[(size_t)(l0 + r) * DD + db + f * 4];
    }
    if (tid < TCH * 4) {
        int r = tid >> 2, f = tid & 3;
        *(float4*)&bs[r * 16 + f * 4] =
            *(const float4*)&bc[(size_t)(l0 + r) * 32 + f * 4];
    }

    const int lane = tid & 63;
    const int w    = tid >> 6;
    const int q    = lane >> 4;
    const int dlo  = (lane & 15) + w * 16;
    const int d    = db + dlo;

    float An[4];
    {
        float4 a = *(const float4*)&A_log[d * NST + q * 4];
        An[0] = -expf(a.x); An[1] = -expf(a.y);
        An[2] = -expf(a.z); An[3] = -expf(a.w);
    }
    __syncthreads();

    float h[4]  = {0.f, 0.f, 0.f, 0.f};
    float Pp[4] = {1.f, 1.f, 1.f, 1.f};
    float xprev = xs[dlo];

    #pragma unroll 4
    for (int ll = 0; ll < TCH; ++ll) {
        float xv  = xs[(ll + 1) * 64 + dlo];
        float dvc = dsv[ll * 64 + dlo];
        float4 Bc = *(const float4*)&bs[ll * 16 + q * 4];

        float xin = 0.5f * (xv + xprev);
        xprev = xv;
        float c0 = 0.5f * dvc;
        float c1 = sqrtf(dvc) * xin;
        float Bs[4] = {Bc.x, Bc.y, Bc.z, Bc.w};
        #pragma unroll
        for (int n = 0; n < 4; ++n) {
            float denom = fmaf(-c0, An[n], 1.0f);
            float inv = __builtin_amdgcn_rcpf(denom);
            float t1 = 2.0f - denom;
            Pp[n] *= t1 * inv;
            h[n] = fmaf(t1, h[n], c1 * Bs[n]) * inv;
        }
    }
    #pragma unroll
    for (int n = 0; n < 4; ++n) {
        int idx = (c * NST + q * 4 + n) * DD + d;
        Pbuf[idx] = Pp[n];
        Hbuf[idx] = h[n];
    }
}

// ---------------------------------------------------------------------------
// Scan pass 2: serial thread-per-series, coalesced, 8-deep prefetch.
// ---------------------------------------------------------------------------
__global__ __launch_bounds__(64) void k_scan2(
    float* __restrict__ Pbuf, const float* __restrict__ Hbuf)
{
    const int s = blockIdx.x * 64 + threadIdx.x;   // series 0..12287 (d-major)
    const int d = s % DD;
    const int n = s / DD;
    const int stride = NST * DD;

    int idx = n * DD + d;
    int idx_pf = idx;
    float p[8], h[8];
    #pragma unroll
    for (int i = 0; i < 8; ++i) {
        p[i] = Pbuf[idx_pf];
        h[i] = Hbuf[idx_pf];
        idx_pf += stride;
    }

    float carry = 0.f;
    for (int g = 0; g < NCH / 8; ++g) {
        float pn[8], hn[8];
        if (g + 1 < NCH / 8) {
            #pragma unroll
            for (int i = 0; i < 8; ++i) {
                pn[i] = Pbuf[idx_pf];
                hn[i] = Hbuf[idx_pf];
                idx_pf += stride;
            }
        }
        #pragma unroll
        for (int i = 0; i < 8; ++i) {
            Pbuf[idx] = carry;
            carry = fmaf(p[i], carry, h[i]);
            idx += stride;
        }
        #pragma unroll
        for (int i = 0; i < 8; ++i) { p[i] = pn[i]; h[i] = hn[i]; }
    }
}

// ---------------------------------------------------------------------------
// Scan pass 3 (TCH=16): redo seeded with carry-in; y = sum C*h + D*x.
// ---------------------------------------------------------------------------
__global__ __launch_bounds__(256, 8) void k_scan3(
    const float* __restrict__ x, const float* __restrict__ delta,
    const float* __restrict__ bc, const float* __restrict__ A_log,
    const float* __restrict__ carryin, const float* __restrict__ D_param,
    float* __restrict__ out)
{
    __shared__ __align__(16) float xs[(TCH + 1) * 64];  // 4.25 KB
    __shared__ __align__(16) float dsv[TCH * 64];       // 4 KB
    __shared__ __align__(16) float bs[TCH * 32];        // 2 KB

    const int tid = threadIdx.x;
    const int db  = blockIdx.x * 64;
    const int c   = blockIdx.y;
    const int l0  = c * TCH;

    for (int i = tid; i < (TCH + 1) * 16; i += 256) {
        int r = i >> 4, f = i & 15;
        int l = l0 - 1 + r;
        float4 v = (l >= 0) ? *(const float4*)&x[(size_t)l * DD + db + f * 4]
                            : make_float4(0.f, 0.f, 0.f, 0.f);
        *(float4*)&xs[r * 64 + f * 4] = v;
    }
    for (int i = tid; i < TCH * 16; i += 256) {
        int r = i >> 4, f = i & 15;
        *(float4*)&dsv[r * 64 + f * 4] =
            *(const float4*)&delta[(size_t)(l0 + r) * DD + db + f * 4];
    }
    if (tid < TCH * 8) {
        int r = tid >> 3, f = tid & 7;
        *(float4*)&bs[r * 32 + f * 4] =
            *(const float4*)&bc[(size_t)(l0 + r) * 32 + f * 4];
    }

    const int lane = tid & 63;
    const int w    = tid >> 6;
    const int q    = lane >> 4;
    const int dlo  = (lane & 15) + w * 16;
    const int d    = db + dlo;

    float An[4];
    {
        float4 a = *(const float4*)&A_log[d * NST + q * 4];
        An[0] = -expf(a.x); An[1] = -expf(a.y);
        An[2] = -expf(a.z); An[3] = -expf(a.w);
    }
    float h[4];
    #pragma unroll
    for (int n = 0; n < 4; ++n)
        h[n] = carryin[(c * NST + q * 4 + n) * DD + d];
    const float Dp = D_param[d];

    __syncthreads();

    float xprev = xs[dlo];
    #pragma unroll 4
    for (int ll = 0; ll < TCH; ++ll) {
        float xv  = xs[(ll + 1) * 64 + dlo];
        float dvc = dsv[ll * 64 + dlo];
        float4 Bc = *(const float4*)&bs[ll * 32 + q * 4];
        float4 Cc = *(const float4*)&bs[ll * 32 + 16 + q * 4];

        float xin = 0.5f * (xv + xprev);
        xprev = xv;
        float c0 = 0.5f * dvc;
        float c1 = sqrtf(dvc) * xin;
        float Bs[4] = {Bc.x, Bc.y, Bc.z, Bc.w};
        float Cs[4] = {Cc.x, Cc.y, Cc.z, Cc.w};
        float y = 0.f;
        #pragma unroll
        for (int n = 0; n < 4; ++n) {
            float denom = fmaf(-c0, An[n], 1.0f);
            float inv = __builtin_amdgcn_rcpf(denom);
            float t1 = 2.0f - denom;
            h[n] = fmaf(t1, h[n], c1 * Bs[n]) * inv;
            y = fmaf(Cs[n], h[n], y);
        }
        y += __shfl_xor(y, 16, 64);
        y += __shfl_xor(y, 32, 64);
        if (q == 0)
            out[(size_t)(l0 + ll) * DD + d] = fmaf(Dp, xv, y);
    }
}

extern "C" void kernel_launch(void* const* d_in, const int* in_sizes, int n_in,
                              void* d_out, int out_size, void* d_ws, size_t ws_size,
                              hipStream_t stream) {
    const float* x         = (const float*)d_in[0];
    const float* A_log     = (const float*)d_in[1];
    const float* D_param   = (const float*)d_in[2];
    const float* W_bc      = (const float*)d_in[3];
    const float* W_dt      = (const float*)d_in[4];
    const float* W_dtp     = (const float*)d_in[5];
    const float* b_dt      = (const float*)d_in[6];
    const float* rms_scale = (const float*)d_in[7];
    float* out = (float*)d_out;

    float* ws    = (float*)d_ws;
    float* delta = ws;                               // L*D
    float* bcbuf = delta + (size_t)LSEQ * DD;        // L*32
    float* Pbuf  = bcbuf + (size_t)LSEQ * 32;        // NCH*16*D
    float* Hbuf  = Pbuf + (size_t)NCH * NST * DD;    // NCH*16*D

    k_proj<<<LSEQ / LTILE, 512, 0, stream>>>(x, W_bc, W_dt, W_dtp, b_dt,
                                             rms_scale, delta, bcbuf);
    k_scan1<<<dim3(DD / 64, NCH), 256, 0, stream>>>(x, delta, bcbuf, A_log,
                                                    Pbuf, Hbuf);
    k_scan2<<<(DD * NST) / 64, 64, 0, stream>>>(Pbuf, Hbuf);
    k_scan3<<<dim3(DD / 64, NCH), 256, 0, stream>>>(x, delta, bcbuf, A_log,
                                                    Pbuf, D_param, out);
}

// Round 14
// 88.735 us; speedup vs baseline: 1.6245x; 1.1232x over previous
//
#include <hip/hip_runtime.h>
#include <math.h>

#define LSEQ 4096
#define DD 768
#define NST 16
#define RNK 48
#define TCH 32
#define NCH (LSEQ / TCH)   // 128 chunks
#define LTILE 8
#define XPAD 772

__device__ __forceinline__ float softplus_f(float z) {
    return fmaxf(z, 0.0f) + log1pf(expf(-fabsf(z)));
}

__device__ __forceinline__ float soft_clamp_f(float v) {
    const float ctr = 5.00005f;
    const float hr  = 4.99995f;
    const float inv_hr = 1.0f / 4.99995f;
    return ctr + hr * tanhf((v - ctr) * inv_hr);
}

__device__ __forceinline__ float wave_sum(float v) {
    #pragma unroll
    for (int m = 32; m >= 1; m >>= 1) v += __shfl_xor(v, m, 64);
    return v;
}

// ---------------------------------------------------------------------------
// Kernel 1 (v6, unchanged): 512 threads, 12-way split-K, 2 blocks/CU.
// fp32 FMA floor ~21 us; MFMA is the only path below ~40 us here.
// ---------------------------------------------------------------------------
__global__ __launch_bounds__(512) void k_proj(
    const float* __restrict__ x, const float* __restrict__ W_bc,
    const float* __restrict__ W_dt, const float* __restrict__ W_dtp,
    const float* __restrict__ b_dt, const float* __restrict__ rms_scale,
    float* __restrict__ delta_out, float* __restrict__ bc_out)
{
    __shared__ __align__(16) float x_s[LTILE][XPAD];     // 24.7 KB
    __shared__ __align__(16) float red[12][LTILE * 80];  // 30 KB
    __shared__ __align__(16) float t_lds[LTILE][RNK];    // 1.5 KB
    __shared__ float red2[8][LTILE];

    const int tid = threadIdx.x;
    const int l0  = blockIdx.x * LTILE;

    {
        const float4* xg = (const float4*)(x + (size_t)l0 * DD);
        #pragma unroll
        for (int k = 0; k < 3; ++k) {
            int idx = k * 512 + tid;
            int li = idx / 192;
            int j  = idx - li * 192;
            *(float4*)&x_s[li][j * 4] = xg[idx];
        }
    }
    __syncthreads();

    if (tid < 480) {
        const int q = tid % 40;
        const int p = tid / 40;
        const int j0 = 2 * q;
        const int dbase = p * 64;
        const int wstride = (j0 < RNK) ? RNK : 32;
        const float* Wb = (j0 < RNK) ? (W_dt + (size_t)dbase * RNK + j0)
                                     : (W_bc + (size_t)dbase * 32 + (j0 - RNK));
        float2 acc[LTILE];
        #pragma unroll
        for (int li = 0; li < LTILE; ++li) acc[li] = make_float2(0.f, 0.f);

        #pragma unroll 2
        for (int c = 0; c < 16; ++c) {
            const int i4 = c * 4;
            const float* Wp = Wb + (size_t)i4 * wstride;
            float2 wd0 = *(const float2*)(Wp);
            float2 wd1 = *(const float2*)(Wp + wstride);
            float2 wd2 = *(const float2*)(Wp + 2 * wstride);
            float2 wd3 = *(const float2*)(Wp + 3 * wstride);
            #pragma unroll
            for (int li = 0; li < LTILE; ++li) {
                float4 xv = *(const float4*)&x_s[li][dbase + i4];
                acc[li].x = fmaf(xv.x, wd0.x, acc[li].x);
                acc[li].y = fmaf(xv.x, wd0.y, acc[li].y);
                acc[li].x = fmaf(xv.y, wd1.x, acc[li].x);
                acc[li].y = fmaf(xv.y, wd1.y, acc[li].y);
                acc[li].x = fmaf(xv.z, wd2.x, acc[li].x);
                acc[li].y = fmaf(xv.z, wd2.y, acc[li].y);
                acc[li].x = fmaf(xv.w, wd3.x, acc[li].x);
                acc[li].y = fmaf(xv.w, wd3.y, acc[li].y);
            }
        }
        #pragma unroll
        for (int li = 0; li < LTILE; ++li)
            *(float2*)&red[p][li * 80 + j0] = acc[li];
    }
    __syncthreads();

    for (int idx = tid; idx < LTILE * 80; idx += 512) {
        float s = 0.f;
        #pragma unroll
        for (int p = 0; p < 12; ++p) s += red[p][idx];
        int li = idx / 80, jj = idx - 80 * li;
        if (jj < RNK) t_lds[li][jj] = s;
        else          bc_out[(size_t)(l0 + li) * 32 + (jj - RNK)] = s;
    }
    __syncthreads();

    const int d0 = tid;
    const int d1 = tid + 512;
    const bool has2 = (tid < 256);

    float z0[LTILE], z1[LTILE];
    {
        float bb0 = b_dt[d0];
        float bb1 = has2 ? b_dt[d1] : 0.f;
        #pragma unroll
        for (int li = 0; li < LTILE; ++li) { z0[li] = bb0; z1[li] = bb1; }
    }
    #pragma unroll 2
    for (int r4 = 0; r4 < RNK; r4 += 4) {
        float w00 = W_dtp[(r4 + 0) * DD + d0];
        float w01 = W_dtp[(r4 + 1) * DD + d0];
        float w02 = W_dtp[(r4 + 2) * DD + d0];
        float w03 = W_dtp[(r4 + 3) * DD + d0];
        float w10 = has2 ? W_dtp[(r4 + 0) * DD + d1] : 0.f;
        float w11 = has2 ? W_dtp[(r4 + 1) * DD + d1] : 0.f;
        float w12 = has2 ? W_dtp[(r4 + 2) * DD + d1] : 0.f;
        float w13 = has2 ? W_dtp[(r4 + 3) * DD + d1] : 0.f;
        #pragma unroll
        for (int li = 0; li < LTILE; ++li) {
            float4 t4 = *(const float4*)&t_lds[li][r4];
            z0[li] = fmaf(t4.x, w00, z0[li]);
            z0[li] = fmaf(t4.y, w01, z0[li]);
            z0[li] = fmaf(t4.z, w02, z0[li]);
            z0[li] = fmaf(t4.w, w03, z0[li]);
            z1[li] = fmaf(t4.x, w10, z1[li]);
            z1[li] = fmaf(t4.y, w11, z1[li]);
            z1[li] = fmaf(t4.z, w12, z1[li]);
            z1[li] = fmaf(t4.w, w13, z1[li]);
        }
    }
    #pragma unroll
    for (int li = 0; li < LTILE; ++li) {
        z0[li] = softplus_f(z0[li]);
        z1[li] = has2 ? softplus_f(z1[li]) : 0.f;
    }
    const int wid = tid >> 6;
    const int lane = tid & 63;
    #pragma unroll
    for (int li = 0; li < LTILE; ++li) {
        float ss = wave_sum(z0[li] * z0[li] + z1[li] * z1[li]);
        if (lane == 0) red2[wid][li] = ss;
    }
    __syncthreads();
    {
        float rs0 = rms_scale[d0];
        float rs1 = has2 ? rms_scale[d1] : 0.f;
        #pragma unroll
        for (int li = 0; li < LTILE; ++li) {
            float tot = 0.f;
            #pragma unroll
            for (int k = 0; k < 8; ++k) tot += red2[k][li];
            float inv = rsqrtf(tot * (1.0f / DD) + 1e-6f);
            delta_out[(size_t)(l0 + li) * DD + d0] = soft_clamp_f(z0[li] * inv * rs0);
            if (has2)
                delta_out[(size_t)(l0 + li) * DD + d1] = soft_clamp_f(z1[li] * inv * rs1);
        }
    }
}

// ---------------------------------------------------------------------------
// Scan pass 1 (TCH=32, staged; sqrt(delta) in LDS; 1 rcp per step via
// product inversion). Block = 64 d x chunk; 1536 blocks = 6/CU resident.
// ---------------------------------------------------------------------------
__global__ __launch_bounds__(256, 8) void k_scan1(
    const float* __restrict__ x, const float* __restrict__ delta,
    const float* __restrict__ bc, const float* __restrict__ A_log,
    float* __restrict__ Pbuf, float* __restrict__ Hbuf)
{
    __shared__ __align__(16) float xs[(TCH + 1) * 64];  // 8.25 KB
    __shared__ __align__(16) float sqv[TCH * 64];       // 8 KB  (sqrt(delta))
    __shared__ __align__(16) float bs[TCH * 16];        // 2 KB

    const int tid = threadIdx.x;
    const int db  = blockIdx.x * 64;
    const int c   = blockIdx.y;
    const int l0  = c * TCH;

    for (int i = tid; i < (TCH + 1) * 16; i += 256) {
        int r = i >> 4, f = i & 15;
        int l = l0 - 1 + r;
        float4 v = (l >= 0) ? *(const float4*)&x[(size_t)l * DD + db + f * 4]
                            : make_float4(0.f, 0.f, 0.f, 0.f);
        *(float4*)&xs[r * 64 + f * 4] = v;
    }
    for (int i = tid; i < TCH * 16; i += 256) {
        int r = i >> 4, f = i & 15;
        float4 v = *(const float4*)&delta[(size_t)(l0 + r) * DD + db + f * 4];
        v.x = sqrtf(v.x); v.y = sqrtf(v.y); v.z = sqrtf(v.z); v.w = sqrtf(v.w);
        *(float4*)&sqv[r * 64 + f * 4] = v;
    }
    if (tid < TCH * 4) {
        int r = tid >> 2, f = tid & 3;
        *(float4*)&bs[r * 16 + f * 4] =
            *(const float4*)&bc[(size_t)(l0 + r) * 32 + f * 4];
    }

    const int lane = tid & 63;
    const int w    = tid >> 6;
    const int q    = lane >> 4;
    const int dlo  = (lane & 15) + w * 16;
    const int d    = db + dlo;

    float An[4];
    {
        float4 a = *(const float4*)&A_log[d * NST + q * 4];
        An[0] = -expf(a.x); An[1] = -expf(a.y);
        An[2] = -expf(a.z); An[3] = -expf(a.w);
    }
    __syncthreads();

    float h[4]  = {0.f, 0.f, 0.f, 0.f};
    float Pp[4] = {1.f, 1.f, 1.f, 1.f};
    float xprev = xs[dlo];

    #pragma unroll 4
    for (int ll = 0; ll < TCH; ++ll) {
        float xv = xs[(ll + 1) * 64 + dlo];
        float sq = sqv[ll * 64 + dlo];
        float4 Bc = *(const float4*)&bs[ll * 16 + q * 4];

        float xin = 0.5f * (xv + xprev);
        xprev = xv;
        float c0 = 0.5f * sq * sq;          // 0.5 * delta
        float c1 = sq * xin;                // sqrt(delta) * xin

        float dn0 = fmaf(-c0, An[0], 1.0f);
        float dn1 = fmaf(-c0, An[1], 1.0f);
        float dn2 = fmaf(-c0, An[2], 1.0f);
        float dn3 = fmaf(-c0, An[3], 1.0f);
        float m01 = dn0 * dn1, m23 = dn2 * dn3;
        float ip  = __builtin_amdgcn_rcpf(m01 * m23);
        float ip01 = ip * m23, ip23 = ip * m01;
        float iv0 = ip01 * dn1, iv1 = ip01 * dn0;
        float iv2 = ip23 * dn3, iv3 = ip23 * dn2;
        float t10 = 2.0f - dn0, t11 = 2.0f - dn1;
        float t12 = 2.0f - dn2, t13 = 2.0f - dn3;

        Pp[0] *= t10 * iv0;
        Pp[1] *= t11 * iv1;
        Pp[2] *= t12 * iv2;
        Pp[3] *= t13 * iv3;
        h[0] = fmaf(t10, h[0], c1 * Bc.x) * iv0;
        h[1] = fmaf(t11, h[1], c1 * Bc.y) * iv1;
        h[2] = fmaf(t12, h[2], c1 * Bc.z) * iv2;
        h[3] = fmaf(t13, h[3], c1 * Bc.w) * iv3;
    }
    #pragma unroll
    for (int n = 0; n < 4; ++n) {
        int idx = (c * NST + q * 4 + n) * DD + d;
        Pbuf[idx] = Pp[n];
        Hbuf[idx] = h[n];
    }
}

// ---------------------------------------------------------------------------
// Scan pass 2: serial thread-per-series, coalesced, 8-deep prefetch.
// NCH=128 -> 16 groups.
// ---------------------------------------------------------------------------
__global__ __launch_bounds__(64) void k_scan2(
    float* __restrict__ Pbuf, const float* __restrict__ Hbuf)
{
    const int s = blockIdx.x * 64 + threadIdx.x;   // series 0..12287 (d-major)
    const int d = s % DD;
    const int n = s / DD;
    const int stride = NST * DD;

    int idx = n * DD + d;
    int idx_pf = idx;
    float p[8], h[8];
    #pragma unroll
    for (int i = 0; i < 8; ++i) {
        p[i] = Pbuf[idx_pf];
        h[i] = Hbuf[idx_pf];
        idx_pf += stride;
    }

    float carry = 0.f;
    for (int g = 0; g < NCH / 8; ++g) {
        float pn[8], hn[8];
        if (g + 1 < NCH / 8) {
            #pragma unroll
            for (int i = 0; i < 8; ++i) {
                pn[i] = Pbuf[idx_pf];
                hn[i] = Hbuf[idx_pf];
                idx_pf += stride;
            }
        }
        #pragma unroll
        for (int i = 0; i < 8; ++i) {
            Pbuf[idx] = carry;
            carry = fmaf(p[i], carry, h[i]);
            idx += stride;
        }
        #pragma unroll
        for (int i = 0; i < 8; ++i) { p[i] = pn[i]; h[i] = hn[i]; }
    }
}

// ---------------------------------------------------------------------------
// Scan pass 3 (TCH=32, staged, sqrt-in-LDS, 1 rcp/step): redo with carry-in;
// y = sum C*h + D*x.
// ---------------------------------------------------------------------------
__global__ __launch_bounds__(256, 8) void k_scan3(
    const float* __restrict__ x, const float* __restrict__ delta,
    const float* __restrict__ bc, const float* __restrict__ A_log,
    const float* __restrict__ carryin, const float* __restrict__ D_param,
    float* __restrict__ out)
{
    __shared__ __align__(16) float xs[(TCH + 1) * 64];  // 8.25 KB
    __shared__ __align__(16) float sqv[TCH * 64];       // 8 KB
    __shared__ __align__(16) float bs[TCH * 32];        // 4 KB (B and C)

    const int tid = threadIdx.x;
    const int db  = blockIdx.x * 64;
    const int c   = blockIdx.y;
    const int l0  = c * TCH;

    for (int i = tid; i < (TCH + 1) * 16; i += 256) {
        int r = i >> 4, f = i & 15;
        int l = l0 - 1 + r;
        float4 v = (l >= 0) ? *(const float4*)&x[(size_t)l * DD + db + f * 4]
                            : make_float4(0.f, 0.f, 0.f, 0.f);
        *(float4*)&xs[r * 64 + f * 4] = v;
    }
    for (int i = tid; i < TCH * 16; i += 256) {
        int r = i >> 4, f = i & 15;
        float4 v = *(const float4*)&delta[(size_t)(l0 + r) * DD + db + f * 4];
        v.x = sqrtf(v.x); v.y = sqrtf(v.y); v.z = sqrtf(v.z); v.w = sqrtf(v.w);
        *(float4*)&sqv[r * 64 + f * 4] = v;
    }
    for (int i = tid; i < TCH * 8; i += 256) {
        int r = i >> 3, f = i & 7;
        *(float4*)&bs[r * 32 + f * 4] =
            *(const float4*)&bc[(size_t)(l0 + r) * 32 + f * 4];
    }

    const int lane = tid & 63;
    const int w    = tid >> 6;
    const int q    = lane >> 4;
    const int dlo  = (lane & 15) + w * 16;
    const int d    = db + dlo;

    float An[4];
    {
        float4 a = *(const float4*)&A_log[d * NST + q * 4];
        An[0] = -expf(a.x); An[1] = -expf(a.y);
        An[2] = -expf(a.z); An[3] = -expf(a.w);
    }
    float h[4];
    #pragma unroll
    for (int n = 0; n < 4; ++n)
        h[n] = carryin[(c * NST + q * 4 + n) * DD + d];
    const float Dp = D_param[d];

    __syncthreads();

    float xprev = xs[dlo];
    #pragma unroll 4
    for (int ll = 0; ll < TCH; ++ll) {
        float xv = xs[(ll + 1) * 64 + dlo];
        float sq = sqv[ll * 64 + dlo];
        float4 Bc = *(const float4*)&bs[ll * 32 + q * 4];
        float4 Cc = *(const float4*)&bs[ll * 32 + 16 + q * 4];

        float xin = 0.5f * (xv + xprev);
        xprev = xv;
        float c0 = 0.5f * sq * sq;
        float c1 = sq * xin;

        float dn0 = fmaf(-c0, An[0], 1.0f);
        float dn1 = fmaf(-c0, An[1], 1.0f);
        float dn2 = fmaf(-c0, An[2], 1.0f);
        float dn3 = fmaf(-c0, An[3], 1.0f);
        float m01 = dn0 * dn1, m23 = dn2 * dn3;
        float ip  = __builtin_amdgcn_rcpf(m01 * m23);
        float ip01 = ip * m23, ip23 = ip * m01;
        float iv0 = ip01 * dn1, iv1 = ip01 * dn0;
        float iv2 = ip23 * dn3, iv3 = ip23 * dn2;
        float t10 = 2.0f - dn0, t11 = 2.0f - dn1;
        float t12 = 2.0f - dn2, t13 = 2.0f - dn3;

        h[0] = fmaf(t10, h[0], c1 * Bc.x) * iv0;
        h[1] = fmaf(t11, h[1], c1 * Bc.y) * iv1;
        h[2] = fmaf(t12, h[2], c1 * Bc.z) * iv2;
        h[3] = fmaf(t13, h[3], c1 * Bc.w) * iv3;

        float y = h[0] * Cc.x;
        y = fmaf(h[1], Cc.y, y);
        y = fmaf(h[2], Cc.z, y);
        y = fmaf(h[3], Cc.w, y);

        y += __shfl_xor(y, 16, 64);
        y += __shfl_xor(y, 32, 64);
        if (q == 0)
            out[(size_t)(l0 + ll) * DD + d] = fmaf(Dp, xv, y);
    }
}

extern "C" void kernel_launch(void* const* d_in, const int* in_sizes, int n_in,
                              void* d_out, int out_size, void* d_ws, size_t ws_size,
                              hipStream_t stream) {
    const float* x         = (const float*)d_in[0];
    const float* A_log     = (const float*)d_in[1];
    const float* D_param   = (const float*)d_in[2];
    const float* W_bc      = (const float*)d_in[3];
    const float* W_dt      = (const float*)d_in[4];
    const float* W_dtp     = (const float*)d_in[5];
    const float* b_dt      = (const float*)d_in[6];
    const float* rms_scale = (const float*)d_in[7];
    float* out = (float*)d_out;

    float* ws    = (float*)d_ws;
    float* delta = ws;                               // L*D
    float* bcbuf = delta + (size_t)LSEQ * DD;        // L*32
    float* Pbuf  = bcbuf + (size_t)LSEQ * 32;        // NCH*16*D = 6.3 MB
    float* Hbuf  = Pbuf + (size_t)NCH * NST * DD;    // NCH*16*D

    k_proj<<<LSEQ / LTILE, 512, 0, stream>>>(x, W_bc, W_dt, W_dtp, b_dt,
                                             rms_scale, delta, bcbuf);
    k_scan1<<<dim3(DD / 64, NCH), 256, 0, stream>>>(x, delta, bcbuf, A_log,
                                                    Pbuf, Hbuf);
    k_scan2<<<(DD * NST) / 64, 64, 0, stream>>>(Pbuf, Hbuf);
    k_scan3<<<dim3(DD / 64, NCH), 256, 0, stream>>>(x, delta, bcbuf, A_log,
                                                    Pbuf, D_param, out);
}